// Round 6
// baseline (1689.249 us; speedup 1.0000x reference)
//
#include <hip/hip_runtime.h>

// PoseSPDecoderKT — round 5: conv GEMM restructured for byte-economy.
// c-step-outer (16) x kk-inner (3): A staged ONCE per c-step into a linear
// per-batch edge-padded LDS buffer (slot s = input row clamp(s-1)); the three
// kk taps read shifted slots (t+kk) — 3x less A traffic. nh-pairs co-located
// per XCD via grid (bg,nh) so the pair shares A through L2. B tiles stay
// fragment-order global_load_lds DMA, rotated per sub-step.
// Packed channel order (unchanged): position p holds channel unpack_c(p) so a
// lane's 8 MFMA fragment elements are 16 contiguous bytes.
// Numerics: same split-bf16 3-product scheme (accumulation order re-tiled).

typedef unsigned short u16;
typedef unsigned short u16x4 __attribute__((ext_vector_type(4)));
typedef unsigned short u16x8 __attribute__((ext_vector_type(8)));
typedef float f32x4 __attribute__((ext_vector_type(4)));
typedef __bf16 bf16x8 __attribute__((ext_vector_type(8)));

__constant__ int KPAR_C[21] = {0,0,0,1,2,3,4,5,6,7,8,9,9,9,12,13,14,16,17,18,19};

__device__ __forceinline__ u16 bf16rne(float v) {
  unsigned b = __builtin_bit_cast(unsigned, v);
  return (u16)((b + 0x7fffu + ((b >> 16) & 1u)) >> 16);
}
__device__ __forceinline__ float bf16tof(u16 h) {
  unsigned b = ((unsigned)h) << 16;
  return __builtin_bit_cast(float, b);
}
__device__ __forceinline__ f32x4 mfma16(u16x8 a, u16x8 b, f32x4 c) {
  return __builtin_amdgcn_mfma_f32_16x16x32_bf16(
      __builtin_bit_cast(bf16x8, a), __builtin_bit_cast(bf16x8, b), c, 0, 0, 0);
}
__device__ __forceinline__ int unpack_c(int p) {
  return (p & ~31) | (((p >> 3) & 3) << 2) | (p & 3) | ((p & 4) << 2);
}
__device__ __forceinline__ void gload_lds16(const void* g, void* l) {
  __builtin_amdgcn_global_load_lds((const __attribute__((address_space(1))) void*)g,
                                   (__attribute__((address_space(3))) void*)l, 16, 0, 0);
}

// ---------------- kwprep: conv weights + tok_w -> fragment-order tiles ------
__global__ __launch_bounds__(256)
void kwprep(const float* __restrict__ conv1_w, const float* __restrict__ up_w,
            const float* __restrict__ tok_w, u16* __restrict__ WF, u16* __restrict__ TWF) {
  int idx = blockIdx.x * 256 + threadIdx.x;
  if (idx < 786432) {
    const int lane = idx & 63;
    int r = idx >> 6;
    const int nf = r & 15; r >>= 4;
    const int ks = r % 48; r /= 48;
    const int p = r & 1; r >>= 1;
    const int nh = r & 1;
    const int L = r >> 1;
    const float* Wsrc = (L == 0) ? conv1_w : (up_w + (size_t)(L - 1) * 786432);
    const int wcol = unpack_c(nh * 256 + nf * 16 + (lane & 15));
    u16x8 o;
#pragma unroll
    for (int e = 0; e < 8; ++e) {
      const int k = ks * 32 + ((lane >> 4) << 2) + (e & 3) + ((e >> 2) << 4);
      const int c = k & 511, kk = k >> 9;
      const float v = Wsrc[(size_t)wcol * 1536 + c * 3 + kk];
      const u16 h = bf16rne(v);
      o[e] = p ? bf16rne(v - bf16tof(h)) : h;
    }
    *(u16x8*)(WF + (size_t)idx * 8) = o;
  } else if (idx < 786432 + 1024) {
    const int i2 = idx - 786432;
    const int lane = i2 & 63;
    const int r = i2 >> 6;
    const int mf = r & 3;
    const int ks = (r >> 2) & 1;
    const int p = r >> 3;
    const int s = mf * 16 + (lane & 15);
    u16x8 o;
#pragma unroll
    for (int e = 0; e < 8; ++e) {
      const int t = ks * 32 + ((lane >> 4) << 2) + (e & 3) + ((e >> 2) << 4);
      const float v = tok_w[s * 64 + t];
      const u16 h = bf16rne(v);
      o[e] = p ? bf16rne(v - bf16tof(h)) : h;
    }
    *(u16x8*)(TWF + (size_t)i2 * 8) = o;
  }
}

// ---------------- kpw1prep: pw1 -> fragment-order split tiles ---------------
__global__ __launch_bounds__(256)
void kpw1prep(const float* __restrict__ pw1, u16* __restrict__ PWF) {
  const int idx = blockIdx.x * 256 + threadIdx.x;
  if (idx >= 2752512) return;
  const int lane = idx & 63;
  const int nf = (idx >> 6) & 15;
  const int ks = (idx >> 10) & 31;
  const int p = (idx >> 15) & 1;
  const int nh = (idx >> 16) & 1;
  const int j = idx >> 17;
  const int w = unpack_c(nh * 256 + nf * 16 + (lane & 15));
  u16x8 o;
#pragma unroll
  for (int e = 0; e < 8; ++e) {
    const int k = ks * 32 + ((lane >> 4) << 2) + (e & 3) + ((e >> 2) << 4);
    const float v = pw1[((size_t)j * 1024 + k) * 512 + w];
    const u16 h = bf16rne(v);
    o[e] = p ? bf16rne(v - bf16tof(h)) : h;
  }
  *(u16x8*)(PWF + (size_t)idx * 8) = o;
}

// ---------------- conv GEMM: c-step-outer / kk-inner, padded A-lin ----------
template <int SLOT, int ROWS, bool SRCF32, bool F32OUT, bool RELU>
__global__ __launch_bounds__(512, 2)
void conv_gemm(const float* __restrict__ xf,
               const u16* __restrict__ ghi, const u16* __restrict__ glo,
               const u16* __restrict__ wl,
               const float* __restrict__ bias,
               u16* __restrict__ ohi, u16* __restrict__ olo,
               float* __restrict__ of32) {
  constexpr int MFW = SLOT / 16;          // m-frags per wave (one batch per m-wave)
  constexpr int SP = ROWS + 2;            // padded slots: s holds row clamp(s-1)
  constexpr int TOT = 32 * SP;            // staged 8B-chunks per plane per c-step / 4b
  constexpr int AIT = (TOT + 511) / 512;
  __shared__ u16x8 Alin[2][2][4][SP][4];  // [buf][plane][batch][slot][16B pair, swz]
  __shared__ u16x8 Bld[2][2][16][64];     // 64 KB

  const int tid = threadIdx.x, lane = tid & 63, w = tid >> 6;
  const int mw = w & 3, nw = w >> 2;      // 4 m-waves (batch) x 2 n-waves
  const int nh = blockIdx.y;
  const int bb0 = blockIdx.x * 4;

  f32x4 acc[MFW][8];
#pragma unroll
  for (int m = 0; m < MFW; ++m)
#pragma unroll
    for (int n = 0; n < 8; ++n) acc[m][n] = (f32x4){0.f, 0.f, 0.f, 0.f};

  float4 rf[AIT];
  u16x4 rh[AIT], rl[AIT];

  auto ALOADg = [&](int cs1) {
#pragma unroll
    for (int it = 0; it < AIT; ++it) {
      const int i = it * 512 + tid;
      if (i < TOT) {
        const int q = i & 7;
        const int s = (i >> 3) % SP;
        const int b = i / (8 * SP);
        int row = s - 1;
        row = row < 0 ? 0 : (row > ROWS - 1 ? ROWS - 1 : row);
        if constexpr (SRCF32) {
          const int ofs = ((q >> 1) << 2) | ((q & 1) << 4);  // packed->actual base
          rf[it] = *(const float4*)(xf + ((size_t)(bb0 + b) * ROWS + row) * 512 +
                                    cs1 * 32 + ofs);
        } else {
          const size_t o = ((size_t)(bb0 + b) * ROWS + row) * 512 + cs1 * 32 + q * 4;
          rh[it] = *(const u16x4*)(ghi + o);
          rl[it] = *(const u16x4*)(glo + o);
        }
      }
    }
  };
  auto AWRITE = [&](int dst) {
#pragma unroll
    for (int it = 0; it < AIT; ++it) {
      const int i = it * 512 + tid;
      if (i < TOT) {
        const int q = i & 7;
        const int s = (i >> 3) % SP;
        const int b = i / (8 * SP);
        const int ci = ((q >> 1) ^ ((s >> 1) & 3)) * 2 + (q & 1);  // swizzled 8B chunk
        u16x4 hv, lv;
        if constexpr (SRCF32) {
          float vv[4] = {rf[it].x, rf[it].y, rf[it].z, rf[it].w};
#pragma unroll
          for (int e = 0; e < 4; ++e) {
            const u16 h = bf16rne(vv[e]);
            hv[e] = h;
            lv[e] = bf16rne(vv[e] - bf16tof(h));
          }
        } else {
          hv = rh[it];
          lv = rl[it];
        }
        ((u16x4*)&Alin[dst][0][b][s][0])[ci] = hv;
        ((u16x4*)&Alin[dst][1][b][s][0])[ci] = lv;
      }
    }
  };
  auto BSTAGE = [&](int u2, int nb) {
    const int ks2 = (u2 % 3) * 16 + (u2 / 3);  // k-tile index = kk*16 + cs
#pragma unroll
    for (int ci = 0; ci < 4; ++ci) {
      const int cch = w + ci * 8;
      const int p = cch >> 4, nf = cch & 15;
      gload_lds16(wl + ((size_t)(((nh * 2 + p) * 48 + ks2) * 16 + nf)) * 512 + lane * 8,
                  &Bld[nb][p][nf][0]);
    }
  };

  ALOADg(0);
  AWRITE(0);
  BSTAGE(0, 0);
  __syncthreads();

  for (int cs = 0; cs < 16; ++cs) {
    const int ab = cs & 1;
    for (int kk = 0; kk < 3; ++kk) {
      const int u = cs * 3 + kk;
      if (u < 47) BSTAGE(u + 1, (u + 1) & 1);
      if (kk == 0 && cs < 15) ALOADg(cs + 1);
      const int bbuf = u & 1;
      u16x8 ah[MFW], al[MFW];
#pragma unroll
      for (int m = 0; m < MFW; ++m) {
        const int t = m * 16 + (lane & 15);
        int s = t + kk;                       // slot s holds row clamp(t-1+kk)
        if (s > ROWS + 1) s = ROWS + 1;       // pad rows (masked at epilogue)
        const int cw = (lane >> 4) ^ ((s >> 1) & 3);
        ah[m] = Alin[ab][0][mw][s][cw];
        al[m] = Alin[ab][1][mw][s][cw];
      }
      __builtin_amdgcn_s_setprio(1);
#pragma unroll
      for (int n = 0; n < 8; ++n) {
        const u16x8 bh = Bld[bbuf][0][nw * 8 + n][lane];
        const u16x8 bl = Bld[bbuf][1][nw * 8 + n][lane];
#pragma unroll
        for (int m = 0; m < MFW; ++m) {
          acc[m][n] = mfma16(ah[m], bh, acc[m][n]);
          acc[m][n] = mfma16(ah[m], bl, acc[m][n]);
          acc[m][n] = mfma16(al[m], bh, acc[m][n]);
        }
      }
      __builtin_amdgcn_s_setprio(0);
      if (kk == 1 && cs < 15) AWRITE(ab ^ 1);
      __syncthreads();
    }
  }

  const int b = bb0 + mw;
#pragma unroll
  for (int m = 0; m < MFW; ++m) {
#pragma unroll
    for (int n = 0; n < 8; ++n) {
      const int col = nh * 256 + nw * 128 + n * 16 + (lane & 15);  // packed slot
      const float bs = bias[unpack_c(col)];
#pragma unroll
      for (int r = 0; r < 4; ++r) {
        const int t = m * 16 + ((lane >> 4) << 2) + r;
        if (t < ROWS) {
          float v = acc[m][n][r] + bs;
          if (RELU) v = fmaxf(v, 0.f);
          const size_t o = ((size_t)b * ROWS + t) * 512 + col;
          if constexpr (F32OUT) {
            of32[o] = v;
          } else {
            const u16 h = bf16rne(v);
            ohi[o] = h;
            olo[o] = bf16rne(v - bf16tof(h));
          }
        }
      }
    }
  }
}

// ---------------- tok_mix (unchanged) ---------------------------------------
__global__ __launch_bounds__(512, 2)
void tok_mix(const u16* __restrict__ h1hi, const u16* __restrict__ h1lo,
             const u16* __restrict__ twf, const float* __restrict__ tok_b,
             u16* __restrict__ g1hi, u16* __restrict__ g1lo) {
  __shared__ float h1f[64][258];
  __shared__ u16x8 twl[2][2][4][64];
  __shared__ float tbl[64];
  const int tid = threadIdx.x, lane = tid & 63, w = tid >> 6;
  const int mw = w & 3, nw = w >> 2;
  const int b = blockIdx.y, ch = blockIdx.x;

  for (int i = tid; i < 1024; i += 512) ((u16x8*)twl)[i] = ((const u16x8*)twf)[i];
  if (tid < 64) tbl[tid] = tok_b[tid];
  for (int i = tid; i < 2048; i += 512) {
    const int t = i >> 5, c8 = (i & 31) * 8;
    const size_t o = ((size_t)b * 64 + t) * 512 + ch * 256 + c8;
    const u16x8 hv = *(const u16x8*)(h1hi + o);
    const u16x8 lv = *(const u16x8*)(h1lo + o);
#pragma unroll
    for (int e = 0; e < 8; ++e) h1f[t][c8 + e] = bf16tof(hv[e]) + bf16tof(lv[e]);
  }
  __syncthreads();

  f32x4 acc2[8];
#pragma unroll
  for (int n = 0; n < 8; ++n) acc2[n] = (f32x4){0.f, 0.f, 0.f, 0.f};
#pragma unroll
  for (int ksI = 0; ksI < 2; ++ksI) {
    const u16x8 ah = twl[0][ksI][mw][lane];
    const u16x8 al = twl[1][ksI][mw][lane];
    const int t0 = ksI * 32 + ((lane >> 4) << 2);
#pragma unroll
    for (int n = 0; n < 8; ++n) {
      const int c = nw * 128 + n * 16 + (lane & 15);
      u16x8 bh, bl;
#pragma unroll
      for (int e = 0; e < 8; ++e) {
        const float v = h1f[t0 + (e & 3) + ((e >> 2) << 4)][c];
        const u16 h = bf16rne(v);
        bh[e] = h;
        bl[e] = bf16rne(v - bf16tof(h));
      }
      acc2[n] = mfma16(ah, bh, acc2[n]);
      acc2[n] = mfma16(ah, bl, acc2[n]);
      acc2[n] = mfma16(al, bh, acc2[n]);
    }
  }
  __syncthreads();
#pragma unroll
  for (int n = 0; n < 8; ++n) {
    const int c = nw * 128 + n * 16 + (lane & 15);
#pragma unroll
    for (int r = 0; r < 4; ++r) {
      const int s = mw * 16 + ((lane >> 4) << 2) + r;
      h1f[s][c] = fmaxf(acc2[n][r] + tbl[s], 0.f);
    }
  }
  __syncthreads();
  const float scale = (float)(64.0 / 50.0);
  for (int i = tid; i < 50 * 256; i += 512) {
    const int s = i >> 8, c = i & 255;
    float coords = fminf(fmaxf(((float)s + 0.5f) * scale - 0.5f, 0.f), 63.f);
    const int lo = (int)floorf(coords);
    const int hi = lo + 1 < 64 ? lo + 1 : 63;
    const float wv = coords - (float)lo;
    const float v = h1f[lo][c] * (1.f - wv) + h1f[hi][c] * wv;
    const u16 h = bf16rne(v);
    const size_t o = ((size_t)b * 50 + s) * 512 + ch * 256 + c;
    g1hi[o] = h;
    g1lo[o] = bf16rne(v - bf16tof(h));
  }
}

// ---------------- ginterp (unchanged) ---------------------------------------
template <int SOUT, int SIN>
__global__ __launch_bounds__(256)
void ginterp(const u16* __restrict__ ahi, const u16* __restrict__ alo,
             u16* __restrict__ ghi, u16* __restrict__ glo) {
  const int idx = blockIdx.x * 256 + threadIdx.x;
  if (idx >= 1024 * SOUT * 64) return;
  const int ch = (idx & 63) * 8;
  const int s = (idx >> 6) % SOUT;
  const int b = (idx >> 6) / SOUT;
  const float scale = (float)((double)SIN / (double)SOUT);
  float coords = fminf(fmaxf(((float)s + 0.5f) * scale - 0.5f, 0.f), (float)(SIN - 1));
  const int lo = (int)floorf(coords);
  const int hi = lo + 1 < SIN ? lo + 1 : SIN - 1;
  const float wv = coords - (float)lo;
  const size_t olo_ = ((size_t)b * SIN + lo) * 512 + ch;
  const size_t ohi_ = ((size_t)b * SIN + hi) * 512 + ch;
  const u16x8 vh0 = *(const u16x8*)(ahi + olo_), vl0 = *(const u16x8*)(alo + olo_);
  const u16x8 vh1 = *(const u16x8*)(ahi + ohi_), vl1 = *(const u16x8*)(alo + ohi_);
  u16x8 oh, ol;
#pragma unroll
  for (int e = 0; e < 8; ++e) {
    const float v0 = bf16tof(vh0[e]) + bf16tof(vl0[e]);
    const float v1 = bf16tof(vh1[e]) + bf16tof(vl1[e]);
    const float v = v0 * (1.f - wv) + v1 * wv;
    const u16 h = bf16rne(v);
    oh[e] = h;
    ol[e] = bf16rne(v - bf16tof(h));
  }
  const size_t oo = ((size_t)b * SOUT + s) * 512 + ch;
  *(u16x8*)(ghi + oo) = oh;
  *(u16x8*)(glo + oo) = ol;
}

// ---------------- k_beta (unchanged) ----------------------------------------
__global__ __launch_bounds__(256)
void k_beta(const float* __restrict__ h, const float* __restrict__ ln_g,
            const float* __restrict__ ln_b, const float* __restrict__ beta_w,
            const float* __restrict__ beta_b, float* __restrict__ out) {
  __shared__ float nbuf[512];
  __shared__ float red[32];
  __shared__ float part[160];
  const int tid = threadIdx.x;
  const int b = blockIdx.x;
  const float* hb = h + (size_t)b * (22 * 512);
  float m0 = 0.f, m1 = 0.f;
  for (int t = 0; t < 22; ++t) {
    m0 += hb[t * 512 + tid];
    m1 += hb[t * 512 + tid + 256];
  }
  m0 *= (1.f / 22.f);
  m1 *= (1.f / 22.f);
  float s = m0 + m1, sq = m0 * m0 + m1 * m1;
  for (int off = 32; off > 0; off >>= 1) {
    s += __shfl_down(s, off);
    sq += __shfl_down(sq, off);
  }
  const int lane = tid & 63, wid = tid >> 6;
  if (lane == 0) { red[wid] = s; red[8 + wid] = sq; }
  __syncthreads();
  if (tid == 0) {
    float S = red[0] + red[1] + red[2] + red[3];
    float Q = red[8] + red[9] + red[10] + red[11];
    float mu = S * (1.f / 512.f);
    float var = Q * (1.f / 512.f) - mu * mu;
    red[16] = mu;
    red[17] = 1.f / sqrtf(var + 1e-5f);
  }
  __syncthreads();
  const float mu = red[16], rs = red[17];
  const int uc = unpack_c(tid);
  nbuf[tid] = (m0 - mu) * rs * ln_g[uc] + ln_b[uc];
  nbuf[tid + 256] = (m1 - mu) * rs * ln_g[uc + 256] + ln_b[uc + 256];
  __syncthreads();
  if (tid < 160) {
    const int o = tid >> 4, l = tid & 15;
    float p = 0.f;
    for (int w = l; w < 512; w += 16) p += nbuf[w] * beta_w[unpack_c(w) * 10 + o];
    part[tid] = p;
  }
  __syncthreads();
  if (tid < 10) {
    float p = beta_b[tid];
#pragma unroll
    for (int l = 0; l < 16; ++l) p += part[tid * 16 + l];
    out[(size_t)b * 10 + tid] = p;
  }
}

// ---------------- k_pose1: per-joint GEMM1 (XCD-paired nh) ------------------
__global__ __launch_bounds__(512, 2)
void k_pose1(const float* __restrict__ hf, const u16* __restrict__ PWF,
             const float* __restrict__ pb1,
             u16* __restrict__ hidhi, u16* __restrict__ hidlo) {
  __shared__ u16x8 Ald[2][2][8][64];
  __shared__ u16x8 Bld[2][2][16][64];
  const int tid = threadIdx.x, lane = tid & 63, w = tid >> 6;
  const int mw = w & 1, nw = w >> 1;
  const int mb = blockIdx.x & 7, nh = blockIdx.x >> 3;  // pair ids differ by 8 -> same XCD
  const int j = blockIdx.y;
  const int bb0 = mb * 128;
  const int par = KPAR_C[j];
  const size_t pwbase = (size_t)(j * 2 + nh) * 524288;

  f32x4 acc[4][4];
#pragma unroll
  for (int m = 0; m < 4; ++m)
#pragma unroll
    for (int n = 0; n < 4; ++n) acc[m][n] = (f32x4){0.f, 0.f, 0.f, 0.f};

  float4 sF0, sF1;

  auto STAGE = [&](int ks, int nb) {
#pragma unroll
    for (int t = 0; t < 4; ++t) {
      const int cc = t * 8 + w;
      const int p = cc >> 4, nf = cc & 15;
      gload_lds16(PWF + pwbase + ((size_t)(p * 32 + ks) * 16 + nf) * 512 + lane * 8,
                  &Bld[nb][p][nf][0]);
    }
  };
  auto LOADSA = [&](int ks) {
    const int row = (ks < 16) ? (j + 1) : par;
    const int b = bb0 + w * 16 + (lane & 15);
    const int pc0 = (ks & 15) * 32 + ((lane >> 4) << 3);
    const float* src = hf + ((size_t)b * 22 + row) * 512 + pc0;
    sF0 = *(const float4*)src;
    sF1 = *(const float4*)(src + 4);
  };
  auto WRITESA = [&](int nb) {
    float vv[8] = {sF0.x, sF0.y, sF0.z, sF0.w, sF1.x, sF1.y, sF1.z, sF1.w};
    u16x8 hv, lv;
#pragma unroll
    for (int e = 0; e < 8; ++e) {
      const u16 h = bf16rne(vv[e]);
      hv[e] = h;
      lv[e] = bf16rne(vv[e] - bf16tof(h));
    }
    Ald[nb][0][w][lane] = hv;
    Ald[nb][1][w][lane] = lv;
  };

  STAGE(0, 0);
  LOADSA(0);
  WRITESA(0);
  __syncthreads();

  for (int ks = 0; ks < 32; ++ks) {
    const int buf = ks & 1;
    if (ks < 31) { STAGE(ks + 1, buf ^ 1); LOADSA(ks + 1); }
    u16x8 ah[4], al[4], bh[4], bl[4];
#pragma unroll
    for (int m = 0; m < 4; ++m) {
      ah[m] = Ald[buf][0][mw * 4 + m][lane];
      al[m] = Ald[buf][1][mw * 4 + m][lane];
    }
#pragma unroll
    for (int n = 0; n < 4; ++n) {
      bh[n] = Bld[buf][0][nw * 4 + n][lane];
      bl[n] = Bld[buf][1][nw * 4 + n][lane];
    }
    __builtin_amdgcn_s_setprio(1);
#pragma unroll
    for (int n = 0; n < 4; ++n)
#pragma unroll
      for (int m = 0; m < 4; ++m) {
        acc[m][n] = mfma16(ah[m], bh[n], acc[m][n]);
        acc[m][n] = mfma16(ah[m], bl[n], acc[m][n]);
        acc[m][n] = mfma16(al[m], bh[n], acc[m][n]);
      }
    __builtin_amdgcn_s_setprio(0);
    if (ks < 31) WRITESA(buf ^ 1);
    __syncthreads();
  }

#pragma unroll
  for (int m = 0; m < 4; ++m) {
#pragma unroll
    for (int n = 0; n < 4; ++n) {
      const int col = nh * 256 + nw * 64 + n * 16 + (lane & 15);
      const float bs = pb1[(size_t)j * 512 + unpack_c(col)];
#pragma unroll
      for (int r = 0; r < 4; ++r) {
        const int b = bb0 + mw * 64 + m * 16 + ((lane >> 4) << 2) + r;
        float v = fmaxf(acc[m][n][r] + bs, 0.f);
        const size_t o = ((size_t)j * 1024 + b) * 512 + col;
        const u16 h = bf16rne(v);
        hidhi[o] = h;
        hidlo[o] = bf16rne(v - bf16tof(h));
      }
    }
  }
}

// ---------------- k_pose2 (unchanged) ---------------------------------------
__global__ __launch_bounds__(256)
void k_pose2(const u16* __restrict__ hidhi, const u16* __restrict__ hidlo,
             const float* __restrict__ pw2, const float* __restrict__ pb2,
             float* __restrict__ out) {
  __shared__ float w2l[3072];
  __shared__ float part[128 * 12];
  const int tid = threadIdx.x;
  const int mb = blockIdx.x, j = blockIdx.y;
  const int bb0 = mb * 128;
  for (int i = tid; i < 3072; i += 256) {
    const int p = i / 6, d = i - p * 6;
    w2l[i] = pw2[(size_t)j * 3072 + unpack_c(p) * 6 + d];
  }
  __syncthreads();

  const int r = tid >> 1, half = tid & 1;
  const int row = bb0 + r;
  const u16* ph = hidhi + ((size_t)j * 1024 + row) * 512 + half * 256;
  const u16* pl = hidlo + ((size_t)j * 1024 + row) * 512 + half * 256;
  float s[6] = {0.f, 0.f, 0.f, 0.f, 0.f, 0.f};
  for (int c = 0; c < 32; ++c) {
    const u16x8 hv = ((const u16x8*)ph)[c];
    const u16x8 lv = ((const u16x8*)pl)[c];
#pragma unroll
    for (int e = 0; e < 8; ++e) {
      const float v = bf16tof(hv[e]) + bf16tof(lv[e]);
      const int hidx = half * 256 + c * 8 + e;
#pragma unroll
      for (int d = 0; d < 6; ++d) s[d] = fmaf(v, w2l[hidx * 6 + d], s[d]);
    }
  }
#pragma unroll
  for (int d = 0; d < 6; ++d) part[r * 12 + half * 6 + d] = s[d];
  __syncthreads();

  if (tid < 128) {
    const int row2 = bb0 + tid;
    float p6[6];
#pragma unroll
    for (int d = 0; d < 6; ++d)
      p6[d] = part[tid * 12 + d] + part[tid * 12 + 6 + d] + pb2[j * 6 + d];
    float* po = out + ((size_t)row2 * 21 + j) * 6;
#pragma unroll
    for (int d = 0; d < 6; ++d) po[d] = p6[d];
    const float a1x = p6[0], a1y = p6[1], a1z = p6[2];
    const float a2x = p6[3], a2y = p6[4], a2z = p6[5];
    const float inv1 = 1.f / sqrtf(a1x * a1x + a1y * a1y + a1z * a1z);
    const float b1x = a1x * inv1, b1y = a1y * inv1, b1z = a1z * inv1;
    const float dot = b1x * a2x + b1y * a2y + b1z * a2z;
    const float px = a2x - dot * b1x, py = a2y - dot * b1y, pz = a2z - dot * b1z;
    const float inv2 = 1.f / sqrtf(px * px + py * py + pz * pz);
    const float b2x = px * inv2, b2y = py * inv2, b2z = pz * inv2;
    const float b3x = b1y * b2z - b1z * b2y;
    const float b3y = b1z * b2x - b1x * b2z;
    const float b3z = b1x * b2y - b1y * b2x;
    float* ro = out + 129024 + ((size_t)row2 * 21 + j) * 9;
    ro[0] = b1x; ro[1] = b1y; ro[2] = b1z;
    ro[3] = b2x; ro[4] = b2y; ro[5] = b2z;
    ro[6] = b3x; ro[7] = b3y; ro[8] = b3z;
  }
}

// ---------------- launch ----------------------------------------------------
extern "C" void kernel_launch(void* const* d_in, const int* in_sizes, int n_in,
                              void* d_out, int out_size, void* d_ws, size_t ws_size,
                              hipStream_t stream) {
  (void)in_sizes; (void)n_in; (void)out_size; (void)ws_size;
  const float* x       = (const float*)d_in[0];
  const float* conv1_w = (const float*)d_in[1];
  const float* conv1_b = (const float*)d_in[2];
  const float* tok_w   = (const float*)d_in[3];
  const float* tok_b   = (const float*)d_in[4];
  const float* up_w    = (const float*)d_in[5];
  const float* up_b    = (const float*)d_in[6];
  const float* ln_g    = (const float*)d_in[7];
  const float* ln_b    = (const float*)d_in[8];
  const float* beta_w  = (const float*)d_in[9];
  const float* beta_b  = (const float*)d_in[10];
  const float* pw1     = (const float*)d_in[11];
  const float* pb1     = (const float*)d_in[12];
  const float* pw2     = (const float*)d_in[13];
  const float* pb2     = (const float*)d_in[14];
  float* outp = (float*)d_out;

  char* base = (char*)d_ws;
  u16* WF  = (u16*)base;                            // 12,582,912 B
  u16* TWF = WF + 6291456;                          // 16,384 B
  u16* PA16 = (u16*)(base + 12599296);              // 134,217,728 B pool A
  u16* PB16 = (u16*)(base + 12599296 + 134217728);  // 104,857,600 B pool B
  u16* h1hi = PA16;            u16* h1lo = PA16 + 33554432;
  u16* a2hi = PA16;            u16* a2lo = PA16 + 26214400;
  u16* a3hi = PA16;            u16* a3lo = PA16 + 18874368;
  float* hf = (float*)PA16;
  u16* g1hi = PB16;            u16* g1lo = PB16 + 26214400;
  u16* g2hi = PB16;            u16* g2lo = PB16 + 18874368;
  u16* g3hi = PB16;            u16* g3lo = PB16 + 11534336;
  u16* PWF   = PB16;
  u16* hidhi = PB16 + 22020096;
  u16* hidlo = PB16 + 33030144;

  const size_t WL = 1572864;

  kwprep<<<3076, 256, 0, stream>>>(conv1_w, up_w, tok_w, WF, TWF);
  conv_gemm<64, 64, true, false, true><<<dim3(256, 2), 512, 0, stream>>>(
      x, nullptr, nullptr, WF, conv1_b, h1hi, h1lo, nullptr);
  tok_mix<<<dim3(2, 1024), 512, 0, stream>>>(h1hi, h1lo, TWF, tok_b, g1hi, g1lo);
  conv_gemm<64, 50, false, false, true><<<dim3(256, 2), 512, 0, stream>>>(
      nullptr, g1hi, g1lo, WF + WL, up_b, a2hi, a2lo, nullptr);
  ginterp<36, 50><<<9216, 256, 0, stream>>>(a2hi, a2lo, g2hi, g2lo);
  conv_gemm<48, 36, false, false, true><<<dim3(256, 2), 512, 0, stream>>>(
      nullptr, g2hi, g2lo, WF + 2 * WL, up_b + 512, a3hi, a3lo, nullptr);
  ginterp<22, 36><<<5632, 256, 0, stream>>>(a3hi, a3lo, g3hi, g3lo);
  conv_gemm<32, 22, false, true, false><<<dim3(256, 2), 512, 0, stream>>>(
      nullptr, g3hi, g3lo, WF + 3 * WL, up_b + 1024, nullptr, nullptr, hf);
  kpw1prep<<<10752, 256, 0, stream>>>(pw1, PWF);
  k_pose1<<<dim3(16, 21), 512, 0, stream>>>(hf, PWF, pb1, hidhi, hidlo);
  k_beta<<<1024, 256, 0, stream>>>(hf, ln_g, ln_b, beta_w, beta_b, outp + 322560);
  k_pose2<<<dim3(8, 21), 256, 0, stream>>>(hidhi, hidlo, pw2, pb2, outp);
}

// Round 7
// 1328.472 us; speedup vs baseline: 1.2716x; 1.2716x over previous
//
#include <hip/hip_runtime.h>

// PoseSPDecoderKT — round 6: c-step-outer/kk-inner conv with PURE-DMA A staging.
// A staged once per c-step (3x fewer A bytes) into linear LDS via
// global_load_lds with pre-swizzled per-lane SOURCE addresses (read-side XOR
// q ^ f(s) matches, involution). conv1 stages raw f32 and splits at frag-read.
// nh pairs mapped to ids differing by 8 (same XCD, concurrent) -> A shared in L2.
// Packed channel order: position p holds channel unpack_c(p) so a lane's 8
// MFMA fragment elements are 16 contiguous bytes.
// Numerics: same split-bf16 3-product scheme as rounds 2-5.

typedef unsigned short u16;
typedef unsigned short u16x4 __attribute__((ext_vector_type(4)));
typedef unsigned short u16x8 __attribute__((ext_vector_type(8)));
typedef float f32x4 __attribute__((ext_vector_type(4)));
typedef __bf16 bf16x8 __attribute__((ext_vector_type(8)));

__constant__ int KPAR_C[21] = {0,0,0,1,2,3,4,5,6,7,8,9,9,9,12,13,14,16,17,18,19};

__device__ __forceinline__ u16 bf16rne(float v) {
  unsigned b = __builtin_bit_cast(unsigned, v);
  return (u16)((b + 0x7fffu + ((b >> 16) & 1u)) >> 16);
}
__device__ __forceinline__ float bf16tof(u16 h) {
  unsigned b = ((unsigned)h) << 16;
  return __builtin_bit_cast(float, b);
}
__device__ __forceinline__ f32x4 mfma16(u16x8 a, u16x8 b, f32x4 c) {
  return __builtin_amdgcn_mfma_f32_16x16x32_bf16(
      __builtin_bit_cast(bf16x8, a), __builtin_bit_cast(bf16x8, b), c, 0, 0, 0);
}
__device__ __forceinline__ int unpack_c(int p) {
  return (p & ~31) | (((p >> 3) & 3) << 2) | (p & 3) | ((p & 4) << 2);
}
__device__ __forceinline__ void gload_lds16(const void* g, void* l) {
  __builtin_amdgcn_global_load_lds((const __attribute__((address_space(1))) void*)g,
                                   (__attribute__((address_space(3))) void*)l, 16, 0, 0);
}

// ---------------- kwprep: conv weights + tok_w -> fragment-order tiles ------
__global__ __launch_bounds__(256)
void kwprep(const float* __restrict__ conv1_w, const float* __restrict__ up_w,
            const float* __restrict__ tok_w, u16* __restrict__ WF, u16* __restrict__ TWF) {
  int idx = blockIdx.x * 256 + threadIdx.x;
  if (idx < 786432) {
    const int lane = idx & 63;
    int r = idx >> 6;
    const int nf = r & 15; r >>= 4;
    const int ks = r % 48; r /= 48;
    const int p = r & 1; r >>= 1;
    const int nh = r & 1;
    const int L = r >> 1;
    const float* Wsrc = (L == 0) ? conv1_w : (up_w + (size_t)(L - 1) * 786432);
    const int wcol = unpack_c(nh * 256 + nf * 16 + (lane & 15));
    u16x8 o;
#pragma unroll
    for (int e = 0; e < 8; ++e) {
      const int k = ks * 32 + ((lane >> 4) << 2) + (e & 3) + ((e >> 2) << 4);
      const int c = k & 511, kk = k >> 9;
      const float v = Wsrc[(size_t)wcol * 1536 + c * 3 + kk];
      const u16 h = bf16rne(v);
      o[e] = p ? bf16rne(v - bf16tof(h)) : h;
    }
    *(u16x8*)(WF + (size_t)idx * 8) = o;
  } else if (idx < 786432 + 1024) {
    const int i2 = idx - 786432;
    const int lane = i2 & 63;
    const int r = i2 >> 6;
    const int mf = r & 3;
    const int ks = (r >> 2) & 1;
    const int p = r >> 3;
    const int s = mf * 16 + (lane & 15);
    u16x8 o;
#pragma unroll
    for (int e = 0; e < 8; ++e) {
      const int t = ks * 32 + ((lane >> 4) << 2) + (e & 3) + ((e >> 2) << 4);
      const float v = tok_w[s * 64 + t];
      const u16 h = bf16rne(v);
      o[e] = p ? bf16rne(v - bf16tof(h)) : h;
    }
    *(u16x8*)(TWF + (size_t)i2 * 8) = o;
  }
}

// ---------------- kpw1prep: pw1 -> fragment-order split tiles ---------------
__global__ __launch_bounds__(256)
void kpw1prep(const float* __restrict__ pw1, u16* __restrict__ PWF) {
  const int idx = blockIdx.x * 256 + threadIdx.x;
  if (idx >= 2752512) return;
  const int lane = idx & 63;
  const int nf = (idx >> 6) & 15;
  const int ks = (idx >> 10) & 31;
  const int p = (idx >> 15) & 1;
  const int nh = (idx >> 16) & 1;
  const int j = idx >> 17;
  const int w = unpack_c(nh * 256 + nf * 16 + (lane & 15));
  u16x8 o;
#pragma unroll
  for (int e = 0; e < 8; ++e) {
    const int k = ks * 32 + ((lane >> 4) << 2) + (e & 3) + ((e >> 2) << 4);
    const float v = pw1[((size_t)j * 1024 + k) * 512 + w];
    const u16 h = bf16rne(v);
    o[e] = p ? bf16rne(v - bf16tof(h)) : h;
  }
  *(u16x8*)(PWF + (size_t)idx * 8) = o;
}

// ---------------- conv GEMM: c-step-outer / kk-inner, DMA-everything --------
// LDS A buffer: linear 16B chunks.
//   bf16: chunk((plane,b,s,pc)) = ((plane*4+b)*SP+s)*4+pc; logical q4 = pc^((s>>1)&3)
//   f32 : chunk((b,s,pc))       = (b*SP+s)*8+pc;          logical q8 = pc^(s&7)
// Slot s holds input row clamp(s-1); frag for (t,kk) reads slot min(t+kk, ROWS+1).
template <int SLOT, int ROWS, bool SRCF32, bool F32OUT, bool RELU>
__global__ __launch_bounds__(512, 2)
void conv_gemm(const float* __restrict__ xf,
               const u16* __restrict__ ghi, const u16* __restrict__ glo,
               const u16* __restrict__ wl,
               const float* __restrict__ bias,
               u16* __restrict__ ohi, u16* __restrict__ olo,
               float* __restrict__ of32) {
  constexpr int MFW = SLOT / 16;
  constexpr int SP = (ROWS + 2 + 3) & ~3;  // padded slot count (mult of 4)
  constexpr int ACH = 32 * SP;             // 16B chunks per A buffer (both layouts)
  constexpr int AIT = (ACH + 511) / 512;
  __shared__ u16x8 Ald[2][ACH];
  __shared__ u16x8 Bld[2][2][16][64];

  const int tid = threadIdx.x, lane = tid & 63, w = tid >> 6;
  const int mw = w & 3, nw = w >> 2;      // 4 m-waves (batch) x 2 n-waves
  const int bid = blockIdx.x;
  const int nh = (bid >> 3) & 1;                       // pair ids differ by 8
  const int bg = ((bid >> 4) << 3) | (bid & 7);        // same XCD (mod 8), concurrent
  const int bb0 = bg * 4;

  f32x4 acc[MFW][8];
#pragma unroll
  for (int m = 0; m < MFW; ++m)
#pragma unroll
    for (int n = 0; n < 8; ++n) acc[m][n] = (f32x4){0.f, 0.f, 0.f, 0.f};

  auto ASTAGE = [&](int cs1, int dst) {
#pragma unroll
    for (int it = 0; it < AIT; ++it) {
      const int base = it * 512 + w * 64;   // wave-uniform
      if (base < ACH) {
        const int f = base + lane;
        if constexpr (SRCF32) {
          const int pc = f & 7;
          const int s = (f >> 3) % SP;
          const int b = (f >> 3) / SP;
          int row = s - 1;
          row = row < 0 ? 0 : (row > ROWS - 1 ? ROWS - 1 : row);
          const int q = pc ^ (s & 7);
          const float* src = xf + ((size_t)(bb0 + b) * ROWS + row) * 512 + cs1 * 32 +
                             ((q >> 1) << 2) + ((q & 1) << 4);
          gload_lds16(src, (u16*)&Ald[dst][0] + (size_t)base * 8);
        } else {
          const int pc = f & 3;
          const int sb = f >> 2;
          const int s = sb % SP;
          const int pb = sb / SP;
          int row = s - 1;
          row = row < 0 ? 0 : (row > ROWS - 1 ? ROWS - 1 : row);
          const int q = pc ^ ((s >> 1) & 3);
          const u16* pl = (pb >> 2) ? glo : ghi;
          const u16* src = pl + ((size_t)(bb0 + (pb & 3)) * ROWS + row) * 512 +
                           cs1 * 32 + q * 8;
          gload_lds16(src, (u16*)&Ald[dst][0] + (size_t)base * 8);
        }
      }
    }
  };
  auto BSTAGE = [&](int u2, int nb) {
    const int ks2 = (u2 % 3) * 16 + (u2 / 3);  // k-tile = kk*16 + cs
#pragma unroll
    for (int ci = 0; ci < 4; ++ci) {
      const int cch = w + ci * 8;
      const int p = cch >> 4, nf = cch & 15;
      gload_lds16(wl + ((size_t)(((nh * 2 + p) * 48 + ks2) * 16 + nf)) * 512 + lane * 8,
                  &Bld[nb][p][nf][0]);
    }
  };

  ASTAGE(0, 0);
  BSTAGE(0, 0);
  __syncthreads();

  const int q = lane >> 4;
  for (int cs = 0; cs < 16; ++cs) {
    const int ab = cs & 1;
#pragma unroll
    for (int kk = 0; kk < 3; ++kk) {
      const int u = cs * 3 + kk;
      if (u < 47) BSTAGE(u + 1, (u + 1) & 1);
      if (kk == 0 && cs < 15) ASTAGE(cs + 1, ab ^ 1);
      u16x8 ah[MFW], al[MFW];
#pragma unroll
      for (int m = 0; m < MFW; ++m) {
        const int t = m * 16 + (lane & 15);
        int s = t + kk;
        if (s > ROWS + 1) s = ROWS + 1;  // junk rows masked at epilogue
        if constexpr (SRCF32) {
          const int f8 = s & 7;
          const f32x4 va = *(const f32x4*)&Ald[ab][(mw * SP + s) * 8 + ((2 * q) ^ f8)];
          const f32x4 vb = *(const f32x4*)&Ald[ab][(mw * SP + s) * 8 + ((2 * q + 1) ^ f8)];
          const float vv[8] = {va[0], va[1], va[2], va[3], vb[0], vb[1], vb[2], vb[3]};
#pragma unroll
          for (int e = 0; e < 8; ++e) {
            const u16 h = bf16rne(vv[e]);
            ah[m][e] = h;
            al[m][e] = bf16rne(vv[e] - bf16tof(h));
          }
        } else {
          const int pc = q ^ ((s >> 1) & 3);
          ah[m] = Ald[ab][((0 + mw) * SP + s) * 4 + pc];
          al[m] = Ald[ab][((4 + mw) * SP + s) * 4 + pc];
        }
      }
      const int bbuf = u & 1;
      __builtin_amdgcn_s_setprio(1);
#pragma unroll
      for (int n = 0; n < 8; ++n) {
        const u16x8 bh = Bld[bbuf][0][nw * 8 + n][lane];
        const u16x8 bl = Bld[bbuf][1][nw * 8 + n][lane];
#pragma unroll
        for (int m = 0; m < MFW; ++m) {
          acc[m][n] = mfma16(ah[m], bh, acc[m][n]);
          acc[m][n] = mfma16(ah[m], bl, acc[m][n]);
          acc[m][n] = mfma16(al[m], bh, acc[m][n]);
        }
      }
      __builtin_amdgcn_s_setprio(0);
      __syncthreads();
    }
  }

  const int b = bb0 + mw;
#pragma unroll
  for (int m = 0; m < MFW; ++m) {
#pragma unroll
    for (int n = 0; n < 8; ++n) {
      const int col = nh * 256 + nw * 128 + n * 16 + (lane & 15);  // packed slot
      const float bs = bias[unpack_c(col)];
#pragma unroll
      for (int r = 0; r < 4; ++r) {
        const int t = m * 16 + ((lane >> 4) << 2) + r;
        if (t < ROWS) {
          float v = acc[m][n][r] + bs;
          if (RELU) v = fmaxf(v, 0.f);
          const size_t o = ((size_t)b * ROWS + t) * 512 + col;
          if constexpr (F32OUT) {
            of32[o] = v;
          } else {
            const u16 h = bf16rne(v);
            ohi[o] = h;
            olo[o] = bf16rne(v - bf16tof(h));
          }
        }
      }
    }
  }
}

// ---------------- tok_mix (unchanged) ---------------------------------------
__global__ __launch_bounds__(512, 2)
void tok_mix(const u16* __restrict__ h1hi, const u16* __restrict__ h1lo,
             const u16* __restrict__ twf, const float* __restrict__ tok_b,
             u16* __restrict__ g1hi, u16* __restrict__ g1lo) {
  __shared__ float h1f[64][258];
  __shared__ u16x8 twl[2][2][4][64];
  __shared__ float tbl[64];
  const int tid = threadIdx.x, lane = tid & 63, w = tid >> 6;
  const int mw = w & 3, nw = w >> 2;
  const int b = blockIdx.y, ch = blockIdx.x;

  for (int i = tid; i < 1024; i += 512) ((u16x8*)twl)[i] = ((const u16x8*)twf)[i];
  if (tid < 64) tbl[tid] = tok_b[tid];
  for (int i = tid; i < 2048; i += 512) {
    const int t = i >> 5, c8 = (i & 31) * 8;
    const size_t o = ((size_t)b * 64 + t) * 512 + ch * 256 + c8;
    const u16x8 hv = *(const u16x8*)(h1hi + o);
    const u16x8 lv = *(const u16x8*)(h1lo + o);
#pragma unroll
    for (int e = 0; e < 8; ++e) h1f[t][c8 + e] = bf16tof(hv[e]) + bf16tof(lv[e]);
  }
  __syncthreads();

  f32x4 acc2[8];
#pragma unroll
  for (int n = 0; n < 8; ++n) acc2[n] = (f32x4){0.f, 0.f, 0.f, 0.f};
#pragma unroll
  for (int ksI = 0; ksI < 2; ++ksI) {
    const u16x8 ah = twl[0][ksI][mw][lane];
    const u16x8 al = twl[1][ksI][mw][lane];
    const int t0 = ksI * 32 + ((lane >> 4) << 2);
#pragma unroll
    for (int n = 0; n < 8; ++n) {
      const int c = nw * 128 + n * 16 + (lane & 15);
      u16x8 bh, bl;
#pragma unroll
      for (int e = 0; e < 8; ++e) {
        const float v = h1f[t0 + (e & 3) + ((e >> 2) << 4)][c];
        const u16 h = bf16rne(v);
        bh[e] = h;
        bl[e] = bf16rne(v - bf16tof(h));
      }
      acc2[n] = mfma16(ah, bh, acc2[n]);
      acc2[n] = mfma16(ah, bl, acc2[n]);
      acc2[n] = mfma16(al, bh, acc2[n]);
    }
  }
  __syncthreads();
#pragma unroll
  for (int n = 0; n < 8; ++n) {
    const int c = nw * 128 + n * 16 + (lane & 15);
#pragma unroll
    for (int r = 0; r < 4; ++r) {
      const int s = mw * 16 + ((lane >> 4) << 2) + r;
      h1f[s][c] = fmaxf(acc2[n][r] + tbl[s], 0.f);
    }
  }
  __syncthreads();
  const float scale = (float)(64.0 / 50.0);
  for (int i = tid; i < 50 * 256; i += 512) {
    const int s = i >> 8, c = i & 255;
    float coords = fminf(fmaxf(((float)s + 0.5f) * scale - 0.5f, 0.f), 63.f);
    const int lo = (int)floorf(coords);
    const int hi = lo + 1 < 64 ? lo + 1 : 63;
    const float wv = coords - (float)lo;
    const float v = h1f[lo][c] * (1.f - wv) + h1f[hi][c] * wv;
    const u16 h = bf16rne(v);
    const size_t o = ((size_t)b * 50 + s) * 512 + ch * 256 + c;
    g1hi[o] = h;
    g1lo[o] = bf16rne(v - bf16tof(h));
  }
}

// ---------------- ginterp (unchanged) ---------------------------------------
template <int SOUT, int SIN>
__global__ __launch_bounds__(256)
void ginterp(const u16* __restrict__ ahi, const u16* __restrict__ alo,
             u16* __restrict__ ghi, u16* __restrict__ glo) {
  const int idx = blockIdx.x * 256 + threadIdx.x;
  if (idx >= 1024 * SOUT * 64) return;
  const int ch = (idx & 63) * 8;
  const int s = (idx >> 6) % SOUT;
  const int b = (idx >> 6) / SOUT;
  const float scale = (float)((double)SIN / (double)SOUT);
  float coords = fminf(fmaxf(((float)s + 0.5f) * scale - 0.5f, 0.f), (float)(SIN - 1));
  const int lo = (int)floorf(coords);
  const int hi = lo + 1 < SIN ? lo + 1 : SIN - 1;
  const float wv = coords - (float)lo;
  const size_t olo_ = ((size_t)b * SIN + lo) * 512 + ch;
  const size_t ohi_ = ((size_t)b * SIN + hi) * 512 + ch;
  const u16x8 vh0 = *(const u16x8*)(ahi + olo_), vl0 = *(const u16x8*)(alo + olo_);
  const u16x8 vh1 = *(const u16x8*)(ahi + ohi_), vl1 = *(const u16x8*)(alo + ohi_);
  u16x8 oh, ol;
#pragma unroll
  for (int e = 0; e < 8; ++e) {
    const float v0 = bf16tof(vh0[e]) + bf16tof(vl0[e]);
    const float v1 = bf16tof(vh1[e]) + bf16tof(vl1[e]);
    const float v = v0 * (1.f - wv) + v1 * wv;
    const u16 h = bf16rne(v);
    oh[e] = h;
    ol[e] = bf16rne(v - bf16tof(h));
  }
  const size_t oo = ((size_t)b * SOUT + s) * 512 + ch;
  *(u16x8*)(ghi + oo) = oh;
  *(u16x8*)(glo + oo) = ol;
}

// ---------------- k_beta (unchanged) ----------------------------------------
__global__ __launch_bounds__(256)
void k_beta(const float* __restrict__ h, const float* __restrict__ ln_g,
            const float* __restrict__ ln_b, const float* __restrict__ beta_w,
            const float* __restrict__ beta_b, float* __restrict__ out) {
  __shared__ float nbuf[512];
  __shared__ float red[32];
  __shared__ float part[160];
  const int tid = threadIdx.x;
  const int b = blockIdx.x;
  const float* hb = h + (size_t)b * (22 * 512);
  float m0 = 0.f, m1 = 0.f;
  for (int t = 0; t < 22; ++t) {
    m0 += hb[t * 512 + tid];
    m1 += hb[t * 512 + tid + 256];
  }
  m0 *= (1.f / 22.f);
  m1 *= (1.f / 22.f);
  float s = m0 + m1, sq = m0 * m0 + m1 * m1;
  for (int off = 32; off > 0; off >>= 1) {
    s += __shfl_down(s, off);
    sq += __shfl_down(sq, off);
  }
  const int lane = tid & 63, wid = tid >> 6;
  if (lane == 0) { red[wid] = s; red[8 + wid] = sq; }
  __syncthreads();
  if (tid == 0) {
    float S = red[0] + red[1] + red[2] + red[3];
    float Q = red[8] + red[9] + red[10] + red[11];
    float mu = S * (1.f / 512.f);
    float var = Q * (1.f / 512.f) - mu * mu;
    red[16] = mu;
    red[17] = 1.f / sqrtf(var + 1e-5f);
  }
  __syncthreads();
  const float mu = red[16], rs = red[17];
  const int uc = unpack_c(tid);
  nbuf[tid] = (m0 - mu) * rs * ln_g[uc] + ln_b[uc];
  nbuf[tid + 256] = (m1 - mu) * rs * ln_g[uc + 256] + ln_b[uc + 256];
  __syncthreads();
  if (tid < 160) {
    const int o = tid >> 4, l = tid & 15;
    float p = 0.f;
    for (int w = l; w < 512; w += 16) p += nbuf[w] * beta_w[unpack_c(w) * 10 + o];
    part[tid] = p;
  }
  __syncthreads();
  if (tid < 10) {
    float p = beta_b[tid];
#pragma unroll
    for (int l = 0; l < 16; ++l) p += part[tid * 16 + l];
    out[(size_t)b * 10 + tid] = p;
  }
}

// ---------------- k_pose1: per-joint GEMM1 (XCD-paired nh) ------------------
__global__ __launch_bounds__(512, 2)
void k_pose1(const float* __restrict__ hf, const u16* __restrict__ PWF,
             const float* __restrict__ pb1,
             u16* __restrict__ hidhi, u16* __restrict__ hidlo) {
  __shared__ u16x8 Ald[2][2][8][64];
  __shared__ u16x8 Bld[2][2][16][64];
  const int tid = threadIdx.x, lane = tid & 63, w = tid >> 6;
  const int mw = w & 1, nw = w >> 1;
  const int mb = blockIdx.x & 7, nh = blockIdx.x >> 3;  // pair ids differ by 8
  const int j = blockIdx.y;
  const int bb0 = mb * 128;
  const int par = KPAR_C[j];
  const size_t pwbase = (size_t)(j * 2 + nh) * 524288;

  f32x4 acc[4][4];
#pragma unroll
  for (int m = 0; m < 4; ++m)
#pragma unroll
    for (int n = 0; n < 4; ++n) acc[m][n] = (f32x4){0.f, 0.f, 0.f, 0.f};

  float4 sF0, sF1;

  auto STAGE = [&](int ks, int nb) {
#pragma unroll
    for (int t = 0; t < 4; ++t) {
      const int cc = t * 8 + w;
      const int p = cc >> 4, nf = cc & 15;
      gload_lds16(PWF + pwbase + ((size_t)(p * 32 + ks) * 16 + nf) * 512 + lane * 8,
                  &Bld[nb][p][nf][0]);
    }
  };
  auto LOADSA = [&](int ks) {
    const int row = (ks < 16) ? (j + 1) : par;
    const int b = bb0 + w * 16 + (lane & 15);
    const int pc0 = (ks & 15) * 32 + ((lane >> 4) << 3);
    const float* src = hf + ((size_t)b * 22 + row) * 512 + pc0;
    sF0 = *(const float4*)src;
    sF1 = *(const float4*)(src + 4);
  };
  auto WRITESA = [&](int nb) {
    float vv[8] = {sF0.x, sF0.y, sF0.z, sF0.w, sF1.x, sF1.y, sF1.z, sF1.w};
    u16x8 hv, lv;
#pragma unroll
    for (int e = 0; e < 8; ++e) {
      const u16 h = bf16rne(vv[e]);
      hv[e] = h;
      lv[e] = bf16rne(vv[e] - bf16tof(h));
    }
    Ald[nb][0][w][lane] = hv;
    Ald[nb][1][w][lane] = lv;
  };

  STAGE(0, 0);
  LOADSA(0);
  WRITESA(0);
  __syncthreads();

  for (int ks = 0; ks < 32; ++ks) {
    const int buf = ks & 1;
    if (ks < 31) { STAGE(ks + 1, buf ^ 1); LOADSA(ks + 1); }
    u16x8 ah[4], al[4], bh[4], bl[4];
#pragma unroll
    for (int m = 0; m < 4; ++m) {
      ah[m] = Ald[buf][0][mw * 4 + m][lane];
      al[m] = Ald[buf][1][mw * 4 + m][lane];
    }
#pragma unroll
    for (int n = 0; n < 4; ++n) {
      bh[n] = Bld[buf][0][nw * 4 + n][lane];
      bl[n] = Bld[buf][1][nw * 4 + n][lane];
    }
    __builtin_amdgcn_s_setprio(1);
#pragma unroll
    for (int n = 0; n < 4; ++n)
#pragma unroll
      for (int m = 0; m < 4; ++m) {
        acc[m][n] = mfma16(ah[m], bh[n], acc[m][n]);
        acc[m][n] = mfma16(ah[m], bl[n], acc[m][n]);
        acc[m][n] = mfma16(al[m], bh[n], acc[m][n]);
      }
    __builtin_amdgcn_s_setprio(0);
    if (ks < 31) WRITESA(buf ^ 1);
    __syncthreads();
  }

#pragma unroll
  for (int m = 0; m < 4; ++m) {
#pragma unroll
    for (int n = 0; n < 4; ++n) {
      const int col = nh * 256 + nw * 64 + n * 16 + (lane & 15);
      const float bs = pb1[(size_t)j * 512 + unpack_c(col)];
#pragma unroll
      for (int r = 0; r < 4; ++r) {
        const int b = bb0 + mw * 64 + m * 16 + ((lane >> 4) << 2) + r;
        float v = fmaxf(acc[m][n][r] + bs, 0.f);
        const size_t o = ((size_t)j * 1024 + b) * 512 + col;
        const u16 h = bf16rne(v);
        hidhi[o] = h;
        hidlo[o] = bf16rne(v - bf16tof(h));
      }
    }
  }
}

// ---------------- k_pose2 (unchanged) ---------------------------------------
__global__ __launch_bounds__(256)
void k_pose2(const u16* __restrict__ hidhi, const u16* __restrict__ hidlo,
             const float* __restrict__ pw2, const float* __restrict__ pb2,
             float* __restrict__ out) {
  __shared__ float w2l[3072];
  __shared__ float part[128 * 12];
  const int tid = threadIdx.x;
  const int mb = blockIdx.x, j = blockIdx.y;
  const int bb0 = mb * 128;
  for (int i = tid; i < 3072; i += 256) {
    const int p = i / 6, d = i - p * 6;
    w2l[i] = pw2[(size_t)j * 3072 + unpack_c(p) * 6 + d];
  }
  __syncthreads();

  const int r = tid >> 1, half = tid & 1;
  const int row = bb0 + r;
  const u16* ph = hidhi + ((size_t)j * 1024 + row) * 512 + half * 256;
  const u16* pl = hidlo + ((size_t)j * 1024 + row) * 512 + half * 256;
  float s[6] = {0.f, 0.f, 0.f, 0.f, 0.f, 0.f};
  for (int c = 0; c < 32; ++c) {
    const u16x8 hv = ((const u16x8*)ph)[c];
    const u16x8 lv = ((const u16x8*)pl)[c];
#pragma unroll
    for (int e = 0; e < 8; ++e) {
      const float v = bf16tof(hv[e]) + bf16tof(lv[e]);
      const int hidx = half * 256 + c * 8 + e;
#pragma unroll
      for (int d = 0; d < 6; ++d) s[d] = fmaf(v, w2l[hidx * 6 + d], s[d]);
    }
  }
#pragma unroll
  for (int d = 0; d < 6; ++d) part[r * 12 + half * 6 + d] = s[d];
  __syncthreads();

  if (tid < 128) {
    const int row2 = bb0 + tid;
    float p6[6];
#pragma unroll
    for (int d = 0; d < 6; ++d)
      p6[d] = part[tid * 12 + d] + part[tid * 12 + 6 + d] + pb2[j * 6 + d];
    float* po = out + ((size_t)row2 * 21 + j) * 6;
#pragma unroll
    for (int d = 0; d < 6; ++d) po[d] = p6[d];
    const float a1x = p6[0], a1y = p6[1], a1z = p6[2];
    const float a2x = p6[3], a2y = p6[4], a2z = p6[5];
    const float inv1 = 1.f / sqrtf(a1x * a1x + a1y * a1y + a1z * a1z);
    const float b1x = a1x * inv1, b1y = a1y * inv1, b1z = a1z * inv1;
    const float dot = b1x * a2x + b1y * a2y + b1z * a2z;
    const float px = a2x - dot * b1x, py = a2y - dot * b1y, pz = a2z - dot * b1z;
    const float inv2 = 1.f / sqrtf(px * px + py * py + pz * pz);
    const float b2x = px * inv2, b2y = py * inv2, b2z = pz * inv2;
    const float b3x = b1y * b2z - b1z * b2y;
    const float b3y = b1z * b2x - b1x * b2z;
    const float b3z = b1x * b2y - b1y * b2x;
    float* ro = out + 129024 + ((size_t)row2 * 21 + j) * 9;
    ro[0] = b1x; ro[1] = b1y; ro[2] = b1z;
    ro[3] = b2x; ro[4] = b2y; ro[5] = b2z;
    ro[6] = b3x; ro[7] = b3y; ro[8] = b3z;
  }
}

// ---------------- launch ----------------------------------------------------
extern "C" void kernel_launch(void* const* d_in, const int* in_sizes, int n_in,
                              void* d_out, int out_size, void* d_ws, size_t ws_size,
                              hipStream_t stream) {
  (void)in_sizes; (void)n_in; (void)out_size; (void)ws_size;
  const float* x       = (const float*)d_in[0];
  const float* conv1_w = (const float*)d_in[1];
  const float* conv1_b = (const float*)d_in[2];
  const float* tok_w   = (const float*)d_in[3];
  const float* tok_b   = (const float*)d_in[4];
  const float* up_w    = (const float*)d_in[5];
  const float* up_b    = (const float*)d_in[6];
  const float* ln_g    = (const float*)d_in[7];
  const float* ln_b    = (const float*)d_in[8];
  const float* beta_w  = (const float*)d_in[9];
  const float* beta_b  = (const float*)d_in[10];
  const float* pw1     = (const float*)d_in[11];
  const float* pb1     = (const float*)d_in[12];
  const float* pw2     = (const float*)d_in[13];
  const float* pb2     = (const float*)d_in[14];
  float* outp = (float*)d_out;

  char* base = (char*)d_ws;
  u16* WF  = (u16*)base;                            // 12,582,912 B
  u16* TWF = WF + 6291456;                          // 16,384 B
  u16* PA16 = (u16*)(base + 12599296);              // 134,217,728 B pool A
  u16* PB16 = (u16*)(base + 12599296 + 134217728);  // 104,857,600 B pool B
  u16* h1hi = PA16;            u16* h1lo = PA16 + 33554432;
  u16* a2hi = PA16;            u16* a2lo = PA16 + 26214400;
  u16* a3hi = PA16;            u16* a3lo = PA16 + 18874368;
  float* hf = (float*)PA16;
  u16* g1hi = PB16;            u16* g1lo = PB16 + 26214400;
  u16* g2hi = PB16;            u16* g2lo = PB16 + 18874368;
  u16* g3hi = PB16;            u16* g3lo = PB16 + 11534336;
  u16* PWF   = PB16;
  u16* hidhi = PB16 + 22020096;
  u16* hidlo = PB16 + 33030144;

  const size_t WL = 1572864;

  kwprep<<<3076, 256, 0, stream>>>(conv1_w, up_w, tok_w, WF, TWF);
  conv_gemm<64, 64, true, false, true><<<512, 512, 0, stream>>>(
      x, nullptr, nullptr, WF, conv1_b, h1hi, h1lo, nullptr);
  tok_mix<<<dim3(2, 1024), 512, 0, stream>>>(h1hi, h1lo, TWF, tok_b, g1hi, g1lo);
  conv_gemm<64, 50, false, false, true><<<512, 512, 0, stream>>>(
      nullptr, g1hi, g1lo, WF + WL, up_b, a2hi, a2lo, nullptr);
  ginterp<36, 50><<<9216, 256, 0, stream>>>(a2hi, a2lo, g2hi, g2lo);
  conv_gemm<48, 36, false, false, true><<<512, 512, 0, stream>>>(
      nullptr, g2hi, g2lo, WF + 2 * WL, up_b + 512, a3hi, a3lo, nullptr);
  ginterp<22, 36><<<5632, 256, 0, stream>>>(a3hi, a3lo, g3hi, g3lo);
  conv_gemm<32, 22, false, true, false><<<512, 512, 0, stream>>>(
      nullptr, g3hi, g3lo, WF + 3 * WL, up_b + 1024, nullptr, nullptr, hf);
  kpw1prep<<<10752, 256, 0, stream>>>(pw1, PWF);
  k_pose1<<<dim3(16, 21), 512, 0, stream>>>(hf, PWF, pb1, hidhi, hidlo);
  k_beta<<<1024, 256, 0, stream>>>(hf, ln_g, ln_b, beta_w, beta_b, outp + 322560);
  k_pose2<<<dim3(8, 21), 256, 0, stream>>>(hidhi, hidlo, pw2, pb2, outp);
}

// Round 8
// 1278.776 us; speedup vs baseline: 1.3210x; 1.0389x over previous
//
#include <hip/hip_runtime.h>

// PoseSPDecoderKT — round 7: counted-vmcnt pipeline (T3/T4) for conv GEMM.
// Raw s_barrier (no implicit vmcnt drain) + s_waitcnt vmcnt(4): B tiles
// triple-buffered (buf = kk), issued 2 steps ahead; A single-buffered per
// c-step behind an A-protect barrier at kk==2. Division-free staging.
// Data layout/swizzles/numerics identical to round 6 (refcheck-passed).

typedef unsigned short u16;
typedef unsigned short u16x4 __attribute__((ext_vector_type(4)));
typedef unsigned short u16x8 __attribute__((ext_vector_type(8)));
typedef float f32x4 __attribute__((ext_vector_type(4)));
typedef __bf16 bf16x8 __attribute__((ext_vector_type(8)));

__constant__ int KPAR_C[21] = {0,0,0,1,2,3,4,5,6,7,8,9,9,9,12,13,14,16,17,18,19};

__device__ __forceinline__ u16 bf16rne(float v) {
  unsigned b = __builtin_bit_cast(unsigned, v);
  return (u16)((b + 0x7fffu + ((b >> 16) & 1u)) >> 16);
}
__device__ __forceinline__ float bf16tof(u16 h) {
  unsigned b = ((unsigned)h) << 16;
  return __builtin_bit_cast(float, b);
}
__device__ __forceinline__ f32x4 mfma16(u16x8 a, u16x8 b, f32x4 c) {
  return __builtin_amdgcn_mfma_f32_16x16x32_bf16(
      __builtin_bit_cast(bf16x8, a), __builtin_bit_cast(bf16x8, b), c, 0, 0, 0);
}
__device__ __forceinline__ int unpack_c(int p) {
  return (p & ~31) | (((p >> 3) & 3) << 2) | (p & 3) | ((p & 4) << 2);
}
__device__ __forceinline__ void gload_lds16(const void* g, void* l) {
  __builtin_amdgcn_global_load_lds((const __attribute__((address_space(1))) void*)g,
                                   (__attribute__((address_space(3))) void*)l, 16, 0, 0);
}

// ---------------- kwprep: conv weights + tok_w -> fragment-order tiles ------
__global__ __launch_bounds__(256)
void kwprep(const float* __restrict__ conv1_w, const float* __restrict__ up_w,
            const float* __restrict__ tok_w, u16* __restrict__ WF, u16* __restrict__ TWF) {
  int idx = blockIdx.x * 256 + threadIdx.x;
  if (idx < 786432) {
    const int lane = idx & 63;
    int r = idx >> 6;
    const int nf = r & 15; r >>= 4;
    const int ks = r % 48; r /= 48;
    const int p = r & 1; r >>= 1;
    const int nh = r & 1;
    const int L = r >> 1;
    const float* Wsrc = (L == 0) ? conv1_w : (up_w + (size_t)(L - 1) * 786432);
    const int wcol = unpack_c(nh * 256 + nf * 16 + (lane & 15));
    u16x8 o;
#pragma unroll
    for (int e = 0; e < 8; ++e) {
      const int k = ks * 32 + ((lane >> 4) << 2) + (e & 3) + ((e >> 2) << 4);
      const int c = k & 511, kk = k >> 9;
      const float v = Wsrc[(size_t)wcol * 1536 + c * 3 + kk];
      const u16 h = bf16rne(v);
      o[e] = p ? bf16rne(v - bf16tof(h)) : h;
    }
    *(u16x8*)(WF + (size_t)idx * 8) = o;
  } else if (idx < 786432 + 1024) {
    const int i2 = idx - 786432;
    const int lane = i2 & 63;
    const int r = i2 >> 6;
    const int mf = r & 3;
    const int ks = (r >> 2) & 1;
    const int p = r >> 3;
    const int s = mf * 16 + (lane & 15);
    u16x8 o;
#pragma unroll
    for (int e = 0; e < 8; ++e) {
      const int t = ks * 32 + ((lane >> 4) << 2) + (e & 3) + ((e >> 2) << 4);
      const float v = tok_w[s * 64 + t];
      const u16 h = bf16rne(v);
      o[e] = p ? bf16rne(v - bf16tof(h)) : h;
    }
    *(u16x8*)(TWF + (size_t)i2 * 8) = o;
  }
}

// ---------------- kpw1prep: pw1 -> fragment-order split tiles ---------------
__global__ __launch_bounds__(256)
void kpw1prep(const float* __restrict__ pw1, u16* __restrict__ PWF) {
  const int idx = blockIdx.x * 256 + threadIdx.x;
  if (idx >= 2752512) return;
  const int lane = idx & 63;
  const int nf = (idx >> 6) & 15;
  const int ks = (idx >> 10) & 31;
  const int p = (idx >> 15) & 1;
  const int nh = (idx >> 16) & 1;
  const int j = idx >> 17;
  const int w = unpack_c(nh * 256 + nf * 16 + (lane & 15));
  u16x8 o;
#pragma unroll
  for (int e = 0; e < 8; ++e) {
    const int k = ks * 32 + ((lane >> 4) << 2) + (e & 3) + ((e >> 2) << 4);
    const float v = pw1[((size_t)j * 1024 + k) * 512 + w];
    const u16 h = bf16rne(v);
    o[e] = p ? bf16rne(v - bf16tof(h)) : h;
  }
  *(u16x8*)(PWF + (size_t)idx * 8) = o;
}

// ---------------- conv GEMM: counted-vmcnt pipeline -------------------------
// Steps v = cs*3+kk (48). B buffer = v%3 = kk (compile-time). B[v+2] issued at
// step v. A (slot buffer, rows clamp(s-1)) staged once per cs at kk==2 behind
// an A-protect barrier. Wait discipline: vmcnt(4) every step (vmcnt(0) at the
// final step only, where no newer issues exist).
template <int SLOT, int ROWS, bool SRCF32, bool F32OUT, bool RELU>
__global__ __launch_bounds__(512, 2)
void conv_gemm(const float* __restrict__ xf,
               const u16* __restrict__ ghi, const u16* __restrict__ glo,
               const u16* __restrict__ wl,
               const float* __restrict__ bias,
               u16* __restrict__ ohi, u16* __restrict__ olo,
               float* __restrict__ of32) {
  constexpr int MFW = SLOT / 16;
  constexpr int SP = ROWS + 2;
  constexpr int AWSP = SRCF32 ? (((SP * 8 + 127) / 128) * 128)   // chunks per batch
                              : (((SP * 4 + 63) / 64) * 64);     // chunks per pb
  constexpr int ACH = SRCF32 ? 4 * AWSP : 8 * AWSP;
  __shared__ u16x8 Ald[ACH];          // single-buffered A (16..40 KB)
  __shared__ u16x8 Bld[3][2][16][64]; // triple-buffered B (96 KB)

  const int tid = threadIdx.x, lane = tid & 63, w = tid >> 6;
  const int mw = w & 3, nw = w >> 2;  // 4 m-waves (batch) x 2 n-waves
  const int bid = blockIdx.x;
  const int nh = (bid >> 3) & 1;                // pair ids differ by 8 -> same XCD
  const int bg = ((bid >> 4) << 3) | (bid & 7);
  const int bb0 = bg * 4;

  f32x4 acc[MFW][8];
#pragma unroll
  for (int m = 0; m < MFW; ++m)
#pragma unroll
    for (int n = 0; n < 8; ++n) acc[m][n] = (f32x4){0.f, 0.f, 0.f, 0.f};

  auto ASTAGE = [&](int cs1) {
    if constexpr (SRCF32) {
      const int bA = w >> 1;
      const int h64 = (w & 1) << 6;
      const float* rowbase = xf + (size_t)(bb0 + bA) * ROWS * 512 + cs1 * 32;
#pragma unroll
      for (int it = 0; it < AWSP / 128; ++it) {
        const int base = it * 128 + h64;       // wave-uniform
        const int o = base + lane;
        int s = o >> 3; s = s > SP - 1 ? SP - 1 : s;
        const int pc = o & 7;
        int row = s - 1; row = row < 0 ? 0 : (row > ROWS - 1 ? ROWS - 1 : row);
        const int q = pc ^ (s & 7);
        gload_lds16(rowbase + (size_t)row * 512 + ((q >> 1) << 2) + ((q & 1) << 4),
                    (u16*)Ald + ((size_t)bA * AWSP + base) * 8);
      }
    } else {
      const int bA = w & 3;
      const u16* pl = (w >= 4) ? glo : ghi;
      const u16* rowbase = pl + (size_t)(bb0 + bA) * ROWS * 512 + cs1 * 32;
#pragma unroll
      for (int it = 0; it < AWSP / 64; ++it) {
        const int base = it * 64;              // wave-uniform
        const int o = base + lane;
        int s = o >> 2; s = s > SP - 1 ? SP - 1 : s;
        const int pc = o & 3;
        int row = s - 1; row = row < 0 ? 0 : (row > ROWS - 1 ? ROWS - 1 : row);
        const int q = pc ^ ((s >> 1) & 3);
        gload_lds16(rowbase + (size_t)row * 512 + q * 8,
                    (u16*)Ald + ((size_t)w * AWSP + base) * 8);
      }
    }
  };
  auto BSTAGE = [&](int cs2, int kk2, int buf) {
#pragma unroll
    for (int ci = 0; ci < 4; ++ci) {
      const int cch = w + ci * 8;
      const int p = cch >> 4, nf = cch & 15;
      gload_lds16(wl + ((size_t)(((nh * 2 + p) * 3 + kk2) * 16 + cs2) * 16 + nf) * 512 + lane * 8,
                  &Bld[buf][p][nf][0]);
    }
  };

  // prologue: A[0] first (older than B01 so vmcnt(4) at step 0 covers it)
  ASTAGE(0);
  BSTAGE(0, 0, 0);
  BSTAGE(0, 1, 1);

  const int q = lane >> 4;
  for (int cs = 0; cs < 16; ++cs) {
#pragma unroll
    for (int kk = 0; kk < 3; ++kk) {
      if (kk == 2 && cs == 15) {
        asm volatile("s_waitcnt vmcnt(0)" ::: "memory");  // no newer issues exist
      } else {
        asm volatile("s_waitcnt vmcnt(4)" ::: "memory");  // leave next-step B in flight
      }
      __builtin_amdgcn_s_barrier();
      // A-frag reads (addresses loop-invariant per m,kk)
      u16x8 ah[MFW], al[MFW];
#pragma unroll
      for (int m = 0; m < MFW; ++m) {
        int s = m * 16 + (lane & 15) + kk;
        if (s > SP - 1) s = SP - 1;  // junk rows masked at epilogue
        if constexpr (SRCF32) {
          const int f8 = s & 7;
          const f32x4 va = *(const f32x4*)&Ald[(size_t)mw * AWSP + s * 8 + ((2 * q) ^ f8)];
          const f32x4 vb = *(const f32x4*)&Ald[(size_t)mw * AWSP + s * 8 + ((2 * q + 1) ^ f8)];
          const float vv[8] = {va[0], va[1], va[2], va[3], vb[0], vb[1], vb[2], vb[3]};
#pragma unroll
          for (int e = 0; e < 8; ++e) {
            const u16 h = bf16rne(vv[e]);
            ah[m][e] = h;
            al[m][e] = bf16rne(vv[e] - bf16tof(h));
          }
        } else {
          const int pc = q ^ ((s >> 1) & 3);
          ah[m] = Ald[(size_t)mw * AWSP + s * 4 + pc];
          al[m] = Ald[(size_t)(4 + mw) * AWSP + s * 4 + pc];
        }
      }
      asm volatile("s_waitcnt lgkmcnt(0)" ::: "memory");
      __builtin_amdgcn_sched_barrier(0);
      if (kk == 2) {
        __builtin_amdgcn_s_barrier();      // A-protect: all waves' A reads done
        if (cs < 15) ASTAGE(cs + 1);       // A issued BEFORE this step's B
      }
      {
        const int nk = (kk + 2) % 3;       // compile-time per kk
        const int nc = cs + (kk + 2) / 3;
        if (nc < 16) BSTAGE(nc, nk, nk);
      }
      __builtin_amdgcn_s_setprio(1);
#pragma unroll
      for (int n = 0; n < 8; ++n) {
        const u16x8 bh = Bld[kk][0][nw * 8 + n][lane];
        const u16x8 bl = Bld[kk][1][nw * 8 + n][lane];
#pragma unroll
        for (int m = 0; m < MFW; ++m) {
          acc[m][n] = mfma16(ah[m], bh, acc[m][n]);
          acc[m][n] = mfma16(ah[m], bl, acc[m][n]);
          acc[m][n] = mfma16(al[m], bh, acc[m][n]);
        }
      }
      __builtin_amdgcn_s_setprio(0);
    }
  }

  const int b = bb0 + mw;
#pragma unroll
  for (int m = 0; m < MFW; ++m) {
#pragma unroll
    for (int n = 0; n < 8; ++n) {
      const int col = nh * 256 + nw * 128 + n * 16 + (lane & 15);  // packed slot
      const float bs = bias[unpack_c(col)];
#pragma unroll
      for (int r = 0; r < 4; ++r) {
        const int t = m * 16 + ((lane >> 4) << 2) + r;
        if (t < ROWS) {
          float v = acc[m][n][r] + bs;
          if (RELU) v = fmaxf(v, 0.f);
          const size_t o = ((size_t)b * ROWS + t) * 512 + col;
          if constexpr (F32OUT) {
            of32[o] = v;
          } else {
            const u16 h = bf16rne(v);
            ohi[o] = h;
            olo[o] = bf16rne(v - bf16tof(h));
          }
        }
      }
    }
  }
}

// ---------------- tok_mix (unchanged) ---------------------------------------
__global__ __launch_bounds__(512, 2)
void tok_mix(const u16* __restrict__ h1hi, const u16* __restrict__ h1lo,
             const u16* __restrict__ twf, const float* __restrict__ tok_b,
             u16* __restrict__ g1hi, u16* __restrict__ g1lo) {
  __shared__ float h1f[64][258];
  __shared__ u16x8 twl[2][2][4][64];
  __shared__ float tbl[64];
  const int tid = threadIdx.x, lane = tid & 63, w = tid >> 6;
  const int mw = w & 3, nw = w >> 2;
  const int b = blockIdx.y, ch = blockIdx.x;

  for (int i = tid; i < 1024; i += 512) ((u16x8*)twl)[i] = ((const u16x8*)twf)[i];
  if (tid < 64) tbl[tid] = tok_b[tid];
  for (int i = tid; i < 2048; i += 512) {
    const int t = i >> 5, c8 = (i & 31) * 8;
    const size_t o = ((size_t)b * 64 + t) * 512 + ch * 256 + c8;
    const u16x8 hv = *(const u16x8*)(h1hi + o);
    const u16x8 lv = *(const u16x8*)(h1lo + o);
#pragma unroll
    for (int e = 0; e < 8; ++e) h1f[t][c8 + e] = bf16tof(hv[e]) + bf16tof(lv[e]);
  }
  __syncthreads();

  f32x4 acc2[8];
#pragma unroll
  for (int n = 0; n < 8; ++n) acc2[n] = (f32x4){0.f, 0.f, 0.f, 0.f};
#pragma unroll
  for (int ksI = 0; ksI < 2; ++ksI) {
    const u16x8 ah = twl[0][ksI][mw][lane];
    const u16x8 al = twl[1][ksI][mw][lane];
    const int t0 = ksI * 32 + ((lane >> 4) << 2);
#pragma unroll
    for (int n = 0; n < 8; ++n) {
      const int c = nw * 128 + n * 16 + (lane & 15);
      u16x8 bh, bl;
#pragma unroll
      for (int e = 0; e < 8; ++e) {
        const float v = h1f[t0 + (e & 3) + ((e >> 2) << 4)][c];
        const u16 h = bf16rne(v);
        bh[e] = h;
        bl[e] = bf16rne(v - bf16tof(h));
      }
      acc2[n] = mfma16(ah, bh, acc2[n]);
      acc2[n] = mfma16(ah, bl, acc2[n]);
      acc2[n] = mfma16(al, bh, acc2[n]);
    }
  }
  __syncthreads();
#pragma unroll
  for (int n = 0; n < 8; ++n) {
    const int c = nw * 128 + n * 16 + (lane & 15);
#pragma unroll
    for (int r = 0; r < 4; ++r) {
      const int s = mw * 16 + ((lane >> 4) << 2) + r;
      h1f[s][c] = fmaxf(acc2[n][r] + tbl[s], 0.f);
    }
  }
  __syncthreads();
  const float scale = (float)(64.0 / 50.0);
  for (int i = tid; i < 50 * 256; i += 512) {
    const int s = i >> 8, c = i & 255;
    float coords = fminf(fmaxf(((float)s + 0.5f) * scale - 0.5f, 0.f), 63.f);
    const int lo = (int)floorf(coords);
    const int hi = lo + 1 < 64 ? lo + 1 : 63;
    const float wv = coords - (float)lo;
    const float v = h1f[lo][c] * (1.f - wv) + h1f[hi][c] * wv;
    const u16 h = bf16rne(v);
    const size_t o = ((size_t)b * 50 + s) * 512 + ch * 256 + c;
    g1hi[o] = h;
    g1lo[o] = bf16rne(v - bf16tof(h));
  }
}

// ---------------- ginterp (unchanged) ---------------------------------------
template <int SOUT, int SIN>
__global__ __launch_bounds__(256)
void ginterp(const u16* __restrict__ ahi, const u16* __restrict__ alo,
             u16* __restrict__ ghi, u16* __restrict__ glo) {
  const int idx = blockIdx.x * 256 + threadIdx.x;
  if (idx >= 1024 * SOUT * 64) return;
  const int ch = (idx & 63) * 8;
  const int s = (idx >> 6) % SOUT;
  const int b = (idx >> 6) / SOUT;
  const float scale = (float)((double)SIN / (double)SOUT);
  float coords = fminf(fmaxf(((float)s + 0.5f) * scale - 0.5f, 0.f), (float)(SIN - 1));
  const int lo = (int)floorf(coords);
  const int hi = lo + 1 < SIN ? lo + 1 : SIN - 1;
  const float wv = coords - (float)lo;
  const size_t olo_ = ((size_t)b * SIN + lo) * 512 + ch;
  const size_t ohi_ = ((size_t)b * SIN + hi) * 512 + ch;
  const u16x8 vh0 = *(const u16x8*)(ahi + olo_), vl0 = *(const u16x8*)(alo + olo_);
  const u16x8 vh1 = *(const u16x8*)(ahi + ohi_), vl1 = *(const u16x8*)(alo + ohi_);
  u16x8 oh, ol;
#pragma unroll
  for (int e = 0; e < 8; ++e) {
    const float v0 = bf16tof(vh0[e]) + bf16tof(vl0[e]);
    const float v1 = bf16tof(vh1[e]) + bf16tof(vl1[e]);
    const float v = v0 * (1.f - wv) + v1 * wv;
    const u16 h = bf16rne(v);
    oh[e] = h;
    ol[e] = bf16rne(v - bf16tof(h));
  }
  const size_t oo = ((size_t)b * SOUT + s) * 512 + ch;
  *(u16x8*)(ghi + oo) = oh;
  *(u16x8*)(glo + oo) = ol;
}

// ---------------- k_beta (unchanged) ----------------------------------------
__global__ __launch_bounds__(256)
void k_beta(const float* __restrict__ h, const float* __restrict__ ln_g,
            const float* __restrict__ ln_b, const float* __restrict__ beta_w,
            const float* __restrict__ beta_b, float* __restrict__ out) {
  __shared__ float nbuf[512];
  __shared__ float red[32];
  __shared__ float part[160];
  const int tid = threadIdx.x;
  const int b = blockIdx.x;
  const float* hb = h + (size_t)b * (22 * 512);
  float m0 = 0.f, m1 = 0.f;
  for (int t = 0; t < 22; ++t) {
    m0 += hb[t * 512 + tid];
    m1 += hb[t * 512 + tid + 256];
  }
  m0 *= (1.f / 22.f);
  m1 *= (1.f / 22.f);
  float s = m0 + m1, sq = m0 * m0 + m1 * m1;
  for (int off = 32; off > 0; off >>= 1) {
    s += __shfl_down(s, off);
    sq += __shfl_down(sq, off);
  }
  const int lane = tid & 63, wid = tid >> 6;
  if (lane == 0) { red[wid] = s; red[8 + wid] = sq; }
  __syncthreads();
  if (tid == 0) {
    float S = red[0] + red[1] + red[2] + red[3];
    float Q = red[8] + red[9] + red[10] + red[11];
    float mu = S * (1.f / 512.f);
    float var = Q * (1.f / 512.f) - mu * mu;
    red[16] = mu;
    red[17] = 1.f / sqrtf(var + 1e-5f);
  }
  __syncthreads();
  const float mu = red[16], rs = red[17];
  const int uc = unpack_c(tid);
  nbuf[tid] = (m0 - mu) * rs * ln_g[uc] + ln_b[uc];
  nbuf[tid + 256] = (m1 - mu) * rs * ln_g[uc + 256] + ln_b[uc + 256];
  __syncthreads();
  if (tid < 160) {
    const int o = tid >> 4, l = tid & 15;
    float p = 0.f;
    for (int w = l; w < 512; w += 16) p += nbuf[w] * beta_w[unpack_c(w) * 10 + o];
    part[tid] = p;
  }
  __syncthreads();
  if (tid < 10) {
    float p = beta_b[tid];
#pragma unroll
    for (int l = 0; l < 16; ++l) p += part[tid * 16 + l];
    out[(size_t)b * 10 + tid] = p;
  }
}

// ---------------- k_pose1 (unchanged from round 6) --------------------------
__global__ __launch_bounds__(512, 2)
void k_pose1(const float* __restrict__ hf, const u16* __restrict__ PWF,
             const float* __restrict__ pb1,
             u16* __restrict__ hidhi, u16* __restrict__ hidlo) {
  __shared__ u16x8 Ald[2][2][8][64];
  __shared__ u16x8 Bld[2][2][16][64];
  const int tid = threadIdx.x, lane = tid & 63, w = tid >> 6;
  const int mw = w & 1, nw = w >> 1;
  const int mb = blockIdx.x & 7, nh = blockIdx.x >> 3;
  const int j = blockIdx.y;
  const int bb0 = mb * 128;
  const int par = KPAR_C[j];
  const size_t pwbase = (size_t)(j * 2 + nh) * 524288;

  f32x4 acc[4][4];
#pragma unroll
  for (int m = 0; m < 4; ++m)
#pragma unroll
    for (int n = 0; n < 4; ++n) acc[m][n] = (f32x4){0.f, 0.f, 0.f, 0.f};

  float4 sF0, sF1;

  auto STAGE = [&](int ks, int nb) {
#pragma unroll
    for (int t = 0; t < 4; ++t) {
      const int cc = t * 8 + w;
      const int p = cc >> 4, nf = cc & 15;
      gload_lds16(PWF + pwbase + ((size_t)(p * 32 + ks) * 16 + nf) * 512 + lane * 8,
                  &Bld[nb][p][nf][0]);
    }
  };
  auto LOADSA = [&](int ks) {
    const int row = (ks < 16) ? (j + 1) : par;
    const int b = bb0 + w * 16 + (lane & 15);
    const int pc0 = (ks & 15) * 32 + ((lane >> 4) << 3);
    const float* src = hf + ((size_t)b * 22 + row) * 512 + pc0;
    sF0 = *(const float4*)src;
    sF1 = *(const float4*)(src + 4);
  };
  auto WRITESA = [&](int nb) {
    float vv[8] = {sF0.x, sF0.y, sF0.z, sF0.w, sF1.x, sF1.y, sF1.z, sF1.w};
    u16x8 hv, lv;
#pragma unroll
    for (int e = 0; e < 8; ++e) {
      const u16 h = bf16rne(vv[e]);
      hv[e] = h;
      lv[e] = bf16rne(vv[e] - bf16tof(h));
    }
    Ald[nb][0][w][lane] = hv;
    Ald[nb][1][w][lane] = lv;
  };

  STAGE(0, 0);
  LOADSA(0);
  WRITESA(0);
  __syncthreads();

  for (int ks = 0; ks < 32; ++ks) {
    const int buf = ks & 1;
    if (ks < 31) { STAGE(ks + 1, buf ^ 1); LOADSA(ks + 1); }
    u16x8 ah[4], al[4], bh[4], bl[4];
#pragma unroll
    for (int m = 0; m < 4; ++m) {
      ah[m] = Ald[buf][0][mw * 4 + m][lane];
      al[m] = Ald[buf][1][mw * 4 + m][lane];
    }
#pragma unroll
    for (int n = 0; n < 4; ++n) {
      bh[n] = Bld[buf][0][nw * 4 + n][lane];
      bl[n] = Bld[buf][1][nw * 4 + n][lane];
    }
    __builtin_amdgcn_s_setprio(1);
#pragma unroll
    for (int n = 0; n < 4; ++n)
#pragma unroll
      for (int m = 0; m < 4; ++m) {
        acc[m][n] = mfma16(ah[m], bh[n], acc[m][n]);
        acc[m][n] = mfma16(ah[m], bl[n], acc[m][n]);
        acc[m][n] = mfma16(al[m], bh[n], acc[m][n]);
      }
    __builtin_amdgcn_s_setprio(0);
    if (ks < 31) WRITESA(buf ^ 1);
    __syncthreads();
  }

#pragma unroll
  for (int m = 0; m < 4; ++m) {
#pragma unroll
    for (int n = 0; n < 4; ++n) {
      const int col = nh * 256 + nw * 64 + n * 16 + (lane & 15);
      const float bs = pb1[(size_t)j * 512 + unpack_c(col)];
#pragma unroll
      for (int r = 0; r < 4; ++r) {
        const int b = bb0 + mw * 64 + m * 16 + ((lane >> 4) << 2) + r;
        float v = fmaxf(acc[m][n][r] + bs, 0.f);
        const size_t o = ((size_t)j * 1024 + b) * 512 + col;
        const u16 h = bf16rne(v);
        hidhi[o] = h;
        hidlo[o] = bf16rne(v - bf16tof(h));
      }
    }
  }
}

// ---------------- k_pose2 (unchanged) ---------------------------------------
__global__ __launch_bounds__(256)
void k_pose2(const u16* __restrict__ hidhi, const u16* __restrict__ hidlo,
             const float* __restrict__ pw2, const float* __restrict__ pb2,
             float* __restrict__ out) {
  __shared__ float w2l[3072];
  __shared__ float part[128 * 12];
  const int tid = threadIdx.x;
  const int mb = blockIdx.x, j = blockIdx.y;
  const int bb0 = mb * 128;
  for (int i = tid; i < 3072; i += 256) {
    const int p = i / 6, d = i - p * 6;
    w2l[i] = pw2[(size_t)j * 3072 + unpack_c(p) * 6 + d];
  }
  __syncthreads();

  const int r = tid >> 1, half = tid & 1;
  const int row = bb0 + r;
  const u16* ph = hidhi + ((size_t)j * 1024 + row) * 512 + half * 256;
  const u16* pl = hidlo + ((size_t)j * 1024 + row) * 512 + half * 256;
  float s[6] = {0.f, 0.f, 0.f, 0.f, 0.f, 0.f};
  for (int c = 0; c < 32; ++c) {
    const u16x8 hv = ((const u16x8*)ph)[c];
    const u16x8 lv = ((const u16x8*)pl)[c];
#pragma unroll
    for (int e = 0; e < 8; ++e) {
      const float v = bf16tof(hv[e]) + bf16tof(lv[e]);
      const int hidx = half * 256 + c * 8 + e;
#pragma unroll
      for (int d = 0; d < 6; ++d) s[d] = fmaf(v, w2l[hidx * 6 + d], s[d]);
    }
  }
#pragma unroll
  for (int d = 0; d < 6; ++d) part[r * 12 + half * 6 + d] = s[d];
  __syncthreads();

  if (tid < 128) {
    const int row2 = bb0 + tid;
    float p6[6];
#pragma unroll
    for (int d = 0; d < 6; ++d)
      p6[d] = part[tid * 12 + d] + part[tid * 12 + 6 + d] + pb2[j * 6 + d];
    float* po = out + ((size_t)row2 * 21 + j) * 6;
#pragma unroll
    for (int d = 0; d < 6; ++d) po[d] = p6[d];
    const float a1x = p6[0], a1y = p6[1], a1z = p6[2];
    const float a2x = p6[3], a2y = p6[4], a2z = p6[5];
    const float inv1 = 1.f / sqrtf(a1x * a1x + a1y * a1y + a1z * a1z);
    const float b1x = a1x * inv1, b1y = a1y * inv1, b1z = a1z * inv1;
    const float dot = b1x * a2x + b1y * a2y + b1z * a2z;
    const float px = a2x - dot * b1x, py = a2y - dot * b1y, pz = a2z - dot * b1z;
    const float inv2 = 1.f / sqrtf(px * px + py * py + pz * pz);
    const float b2x = px * inv2, b2y = py * inv2, b2z = pz * inv2;
    const float b3x = b1y * b2z - b1z * b2y;
    const float b3y = b1z * b2x - b1x * b2z;
    const float b3z = b1x * b2y - b1y * b2x;
    float* ro = out + 129024 + ((size_t)row2 * 21 + j) * 9;
    ro[0] = b1x; ro[1] = b1y; ro[2] = b1z;
    ro[3] = b2x; ro[4] = b2y; ro[5] = b2z;
    ro[6] = b3x; ro[7] = b3y; ro[8] = b3z;
  }
}

// ---------------- launch ----------------------------------------------------
extern "C" void kernel_launch(void* const* d_in, const int* in_sizes, int n_in,
                              void* d_out, int out_size, void* d_ws, size_t ws_size,
                              hipStream_t stream) {
  (void)in_sizes; (void)n_in; (void)out_size; (void)ws_size;
  const float* x       = (const float*)d_in[0];
  const float* conv1_w = (const float*)d_in[1];
  const float* conv1_b = (const float*)d_in[2];
  const float* tok_w   = (const float*)d_in[3];
  const float* tok_b   = (const float*)d_in[4];
  const float* up_w    = (const float*)d_in[5];
  const float* up_b    = (const float*)d_in[6];
  const float* ln_g    = (const float*)d_in[7];
  const float* ln_b    = (const float*)d_in[8];
  const float* beta_w  = (const float*)d_in[9];
  const float* beta_b  = (const float*)d_in[10];
  const float* pw1     = (const float*)d_in[11];
  const float* pb1     = (const float*)d_in[12];
  const float* pw2     = (const float*)d_in[13];
  const float* pb2     = (const float*)d_in[14];
  float* outp = (float*)d_out;

  char* base = (char*)d_ws;
  u16* WF  = (u16*)base;                            // 12,582,912 B
  u16* TWF = WF + 6291456;                          // 16,384 B
  u16* PA16 = (u16*)(base + 12599296);              // 134,217,728 B pool A
  u16* PB16 = (u16*)(base + 12599296 + 134217728);  // 104,857,600 B pool B
  u16* h1hi = PA16;            u16* h1lo = PA16 + 33554432;
  u16* a2hi = PA16;            u16* a2lo = PA16 + 26214400;
  u16* a3hi = PA16;            u16* a3lo = PA16 + 18874368;
  float* hf = (float*)PA16;
  u16* g1hi = PB16;            u16* g1lo = PB16 + 26214400;
  u16* g2hi = PB16;            u16* g2lo = PB16 + 18874368;
  u16* g3hi = PB16;            u16* g3lo = PB16 + 11534336;
  u16* PWF   = PB16;
  u16* hidhi = PB16 + 22020096;
  u16* hidlo = PB16 + 33030144;

  const size_t WL = 1572864;

  kwprep<<<3076, 256, 0, stream>>>(conv1_w, up_w, tok_w, WF, TWF);
  conv_gemm<64, 64, true, false, true><<<512, 512, 0, stream>>>(
      x, nullptr, nullptr, WF, conv1_b, h1hi, h1lo, nullptr);
  tok_mix<<<dim3(2, 1024), 512, 0, stream>>>(h1hi, h1lo, TWF, tok_b, g1hi, g1lo);
  conv_gemm<64, 50, false, false, true><<<512, 512, 0, stream>>>(
      nullptr, g1hi, g1lo, WF + WL, up_b, a2hi, a2lo, nullptr);
  ginterp<36, 50><<<9216, 256, 0, stream>>>(a2hi, a2lo, g2hi, g2lo);
  conv_gemm<48, 36, false, false, true><<<512, 512, 0, stream>>>(
      nullptr, g2hi, g2lo, WF + 2 * WL, up_b + 512, a3hi, a3lo, nullptr);
  ginterp<22, 36><<<5632, 256, 0, stream>>>(a3hi, a3lo, g3hi, g3lo);
  conv_gemm<32, 22, false, true, false><<<512, 512, 0, stream>>>(
      nullptr, g3hi, g3lo, WF + 3 * WL, up_b + 1024, nullptr, nullptr, hf);
  kpw1prep<<<10752, 256, 0, stream>>>(pw1, PWF);
  k_pose1<<<dim3(16, 21), 512, 0, stream>>>(hf, PWF, pb1, hidhi, hidlo);
  k_beta<<<1024, 256, 0, stream>>>(hf, ln_g, ln_b, beta_w, beta_b, outp + 322560);
  k_pose2<<<dim3(8, 21), 256, 0, stream>>>(hidhi, hidlo, pw2, pb2, outp);
}